// Round 1
// baseline (498.271 us; speedup 1.0000x reference)
//
#include <hip/hip_runtime.h>
#include <math.h>

#define B 8
#define S 1024
#define D 768
#define H 12
#define V 50257
#define DFF 3072
#define HD (H*D)      // 9216
#define SLO 1012      // first s needed (head 11, last 12 positions of y feed x row 1023)
#define NS 12

// workspace layout (float offsets)
#define OFF_EMEAN 0                     // 768   (atomic sum; divide by V on read)
#define OFF_A     768                   // B*NS*D = 73728 (atomic)
#define OFF_GQ    (OFF_A + B*NS*D)      // NS*D = 9216
#define OFF_SC    (OFF_GQ + NS*D)       // NS*S = 12288 (scores -> attn in place)
#define OFF_YV    (OFF_SC + NS*S)       // B*HD = 73728
#define OFF_YO    (OFF_YV + B*HD)       // B*D = 6144
#define OFF_G     (OFF_YO + B*D)        // B*DFF = 24576
#define OFF_X     (OFF_G + B*DFF)       // B*D = 6144

__device__ __forceinline__ float wsum(float v) {
    v += __shfl_xor(v, 1, 64);
    v += __shfl_xor(v, 2, 64);
    v += __shfl_xor(v, 4, 64);
    v += __shfl_xor(v, 8, 64);
    v += __shfl_xor(v, 16, 64);
    v += __shfl_xor(v, 32, 64);
    return v;
}

// ---- K1: column sums of wte (for e_mean). grid (3, 128) x 256
__global__ __launch_bounds__(256) void k1_emean(const float* __restrict__ wte,
                                                float* __restrict__ ws) {
    const int col = blockIdx.x * 256 + threadIdx.x;           // < 768
    const int v0  = blockIdx.y * 393;
    const int v1  = min(V, v0 + 393);
    float s = 0.f;
    for (int v = v0; v < v1; ++v) s += wte[(size_t)v * D + col];
    atomicAdd(&ws[OFF_EMEAN + col], s);
}

// ---- K2a: gq[s12,d] = wpe[s+1,d]*wq[11,d]*wk[11,d]. grid 36 x 256
__global__ __launch_bounds__(256) void k2a_gq(const float* __restrict__ wpe,
                                              const float* __restrict__ wq,
                                              const float* __restrict__ wk,
                                              float* __restrict__ ws) {
    int i = blockIdx.x * 256 + threadIdx.x;                   // < 9216
    int s12 = i / D, d = i % D;
    ws[OFF_GQ + i] = wpe[(SLO + s12 + 1) * D + d] * wq[11 * D + d] * wk[11 * D + d];
}

// ---- K2b: scores[s12,t] = p[t,:] . gq[s12,:].  wave per t. grid 256 x 256
__global__ __launch_bounds__(256) void k2b_scores(const float* __restrict__ wpe,
                                                  float* __restrict__ ws) {
    const int lane = threadIdx.x & 63;
    const int t = (blockIdx.x * 256 + threadIdx.x) >> 6;      // 0..1023
    float4 p[3];
#pragma unroll
    for (int i = 0; i < 3; ++i)
        p[i] = *reinterpret_cast<const float4*>(wpe + t * D + 4 * lane + 256 * i);
    float acc[12];
#pragma unroll
    for (int s12 = 0; s12 < 12; ++s12) {
        float a = 0.f;
#pragma unroll
        for (int i = 0; i < 3; ++i) {
            float4 g = *reinterpret_cast<const float4*>(ws + OFF_GQ + s12 * D + 4 * lane + 256 * i);
            a += p[i].x * g.x + p[i].y * g.y + p[i].z * g.z + p[i].w * g.w;
        }
        acc[s12] = a;
    }
#pragma unroll
    for (int s12 = 0; s12 < 12; ++s12) acc[s12] = wsum(acc[s12]);
    float v = acc[0];
#pragma unroll
    for (int j = 1; j < 12; ++j) if (lane == j) v = acc[j];
    if (lane < 12) ws[OFF_SC + lane * S + t] = v;
}

// ---- K3: softmax rows (masked t<=s), writes attn in place (0 beyond). grid 12 x 256
__global__ __launch_bounds__(256) void k3_softmax(float* __restrict__ ws) {
    __shared__ float red[256];
    const int s12 = blockIdx.x, tid = threadIdx.x;
    const int n = SLO + s12 + 1;                              // valid t count
    float* sc = ws + OFF_SC + s12 * S;
    float m = -1e30f;
#pragma unroll
    for (int k = 0; k < 4; ++k) { int t = tid + 256 * k; if (t < n) m = fmaxf(m, sc[t]); }
    red[tid] = m; __syncthreads();
    for (int off = 128; off; off >>= 1) { if (tid < off) red[tid] = fmaxf(red[tid], red[tid + off]); __syncthreads(); }
    float mx = red[0]; __syncthreads();
    float sum = 0.f;
#pragma unroll
    for (int k = 0; k < 4; ++k) { int t = tid + 256 * k; if (t < n) sum += expf(sc[t] - mx); }
    red[tid] = sum; __syncthreads();
    for (int off = 128; off; off >>= 1) { if (tid < off) red[tid] += red[tid + off]; __syncthreads(); }
    float inv = 1.0f / red[0];
#pragma unroll
    for (int k = 0; k < 4; ++k) {
        int t = tid + 256 * k;
        sc[t] = (t < n) ? expf(sc[t] - mx) * inv : 0.0f;
    }
}

// ---- K4: A[b,s12,d] += sum_t attn[s12,t]*wte[idx[b,t],d]. grid (3,8,16) x 256
__global__ __launch_bounds__(256) void k4_accA(const int* __restrict__ idx,
                                               const float* __restrict__ wte,
                                               float* __restrict__ ws) {
    __shared__ float wl[64 * 12];
    const int cx = blockIdx.x, b = blockIdx.y, tc = blockIdx.z;
    const int tid = threadIdx.x;
    for (int i = tid; i < 768; i += 256) {
        int tl = i / 12, s12 = i % 12;
        wl[i] = ws[OFF_SC + s12 * S + tc * 64 + tl];
    }
    __syncthreads();
    const int col = cx * 256 + tid;
    float acc[12] = {0.f,0.f,0.f,0.f,0.f,0.f,0.f,0.f,0.f,0.f,0.f,0.f};
    for (int tl = 0; tl < 64; ++tl) {
        int row = idx[b * S + tc * 64 + tl];
        float val = wte[(size_t)row * D + col];
        const float4* w4 = reinterpret_cast<const float4*>(&wl[tl * 12]);
        float4 w0 = w4[0], w1 = w4[1], w2 = w4[2];
        acc[0] += w0.x * val;  acc[1] += w0.y * val;  acc[2]  += w0.z * val;  acc[3]  += w0.w * val;
        acc[4] += w1.x * val;  acc[5] += w1.y * val;  acc[6]  += w1.z * val;  acc[7]  += w1.w * val;
        acc[8] += w2.x * val;  acc[9] += w2.y * val;  acc[10] += w2.z * val;  acc[11] += w2.w * val;
    }
#pragma unroll
    for (int s12 = 0; s12 < 12; ++s12)
        atomicAdd(&ws[OFF_A + (b * NS + s12) * D + col], acc[s12]);
}

// ---- K5: yv[b, s12*768+d] = (A - e_mean)*wv[11,d]*invn[s]*w_lr[11]. grid 288 x 256
__global__ __launch_bounds__(256) void k5_yv(const float* __restrict__ wv,
                                             const float* __restrict__ wlr,
                                             float* __restrict__ ws) {
    int i = blockIdx.x * 256 + threadIdx.x;                   // < 73728
    int b = i / HD, f = i % HD, s12 = f / D, d = f % D;
    float em = ws[OFF_EMEAN + d] * (1.0f / V);
    float A  = ws[OFF_A + (b * NS + s12) * D + d];
    float invn = 1.0f / (float)(SLO + s12 + 1);
    ws[OFF_YV + i] = (A - em) * wv[11 * D + d] * invn * wlr[11];
}

// ---- K5b: yo[b,d] initialized to sb[d] (batch-summed b_term at s=1023). grid 3 x 256
__global__ __launch_bounds__(256) void k5b_sb(const int* __restrict__ idx,
                                              const float* __restrict__ wte,
                                              float* __restrict__ ws) {
    int d = blockIdx.x * 256 + threadIdx.x;                   // < 768
    float em = ws[OFF_EMEAN + d] * (1.0f / V);
    float s = 0.f;
#pragma unroll
    for (int b = 0; b < 8; ++b) {
        int row = idx[b * S + (S - 1)];
        s += wte[(size_t)row * D + d];
    }
    float sb = (s - 8.0f * em) * (1.0f / (float)S);
#pragma unroll
    for (int b = 0; b < 8; ++b) ws[OFF_YO + b * D + d] = sb;
}

// ---- K6: yo[b,d'] += sum_f yv[b,f]*w_o[d',f].  wave = 2 rows x 1/4 of k. grid 384 x 256
__global__ __launch_bounds__(256) void k6_wo(const float* __restrict__ w_o,
                                             float* __restrict__ ws) {
    const int lane = threadIdx.x & 63;
    const int wid = (blockIdx.x * 256 + threadIdx.x) >> 6;    // 0..1535
    const int kc = wid & 3;
    const int r0 = (wid >> 2) * 2;                            // 0..766
    const int kbase = kc * 2304;
    float acc[2][8] = {{0}};
#pragma unroll
    for (int i = 0; i < 9; ++i) {
        int k = kbase + 4 * lane + 256 * i;
        float4 a0 = *reinterpret_cast<const float4*>(w_o + (size_t)r0 * HD + k);
        float4 a1 = *reinterpret_cast<const float4*>(w_o + (size_t)(r0 + 1) * HD + k);
#pragma unroll
        for (int b = 0; b < 8; ++b) {
            float4 y = *reinterpret_cast<const float4*>(ws + OFF_YV + b * HD + k);
            acc[0][b] += a0.x * y.x + a0.y * y.y + a0.z * y.z + a0.w * y.w;
            acc[1][b] += a1.x * y.x + a1.y * y.y + a1.z * y.z + a1.w * y.w;
        }
    }
#pragma unroll
    for (int r = 0; r < 2; ++r)
#pragma unroll
        for (int b = 0; b < 8; ++b) acc[r][b] = wsum(acc[r][b]);
    float v = acc[0][0];
#pragma unroll
    for (int l = 1; l < 16; ++l) if (lane == l) v = acc[l >> 3][l & 7];
    if (lane < 16) atomicAdd(&ws[OFF_YO + (lane & 7) * D + r0 + (lane >> 3)], v);
}

// ---- K7: g[b,f] = gelu(sum_d yo[b,d]*w1[f,d]).  wave per f. grid 768 x 256
__global__ __launch_bounds__(256) void k7_mlp1(const float* __restrict__ w1,
                                               float* __restrict__ ws) {
    const int lane = threadIdx.x & 63;
    const int f = (blockIdx.x * 256 + threadIdx.x) >> 6;      // 0..3071
    float acc[8] = {0};
#pragma unroll
    for (int i = 0; i < 3; ++i) {
        int dcol = 4 * lane + 256 * i;
        float4 w = *reinterpret_cast<const float4*>(w1 + (size_t)f * D + dcol);
#pragma unroll
        for (int b = 0; b < 8; ++b) {
            float4 y = *reinterpret_cast<const float4*>(ws + OFF_YO + b * D + dcol);
            acc[b] += w.x * y.x + w.y * y.y + w.z * y.z + w.w * y.w;
        }
    }
#pragma unroll
    for (int b = 0; b < 8; ++b) acc[b] = wsum(acc[b]);
    float v = acc[0];
#pragma unroll
    for (int j = 1; j < 8; ++j) if (lane == j) v = acc[j];
    if (lane < 8) {
        float g = 0.5f * v * (1.0f + erff(v * 0.70710678118654752f));
        ws[OFF_G + lane * DFF + f] = g;
    }
}

// ---- K8: x[b,d] = yo[b,d] + sum_f g[b,f]*w2[d,f].  wave per d. grid 192 x 256
__global__ __launch_bounds__(256) void k8_mlp2(const float* __restrict__ w2,
                                               float* __restrict__ ws) {
    const int lane = threadIdx.x & 63;
    const int dd = (blockIdx.x * 256 + threadIdx.x) >> 6;     // 0..767
    float acc[8] = {0};
#pragma unroll
    for (int i = 0; i < 12; ++i) {
        int fcol = 4 * lane + 256 * i;
        float4 w = *reinterpret_cast<const float4*>(w2 + (size_t)dd * DFF + fcol);
#pragma unroll
        for (int b = 0; b < 8; ++b) {
            float4 g = *reinterpret_cast<const float4*>(ws + OFF_G + b * DFF + fcol);
            acc[b] += w.x * g.x + w.y * g.y + w.z * g.z + w.w * g.w;
        }
    }
#pragma unroll
    for (int b = 0; b < 8; ++b) acc[b] = wsum(acc[b]);
    float v = acc[0];
#pragma unroll
    for (int j = 1; j < 8; ++j) if (lane == j) v = acc[j];
    if (lane < 8) ws[OFF_X + lane * D + dd] = ws[OFF_YO + lane * D + dd] + v;
}

// ---- K9: logits[b,j] = x[b,:] . wte[j,:].  wave per row, x in registers. grid 768 x 256
__global__ __launch_bounds__(256) void k9_logits(const float* __restrict__ wte,
                                                 const float* __restrict__ ws,
                                                 float* __restrict__ out) {
    const int lane = threadIdx.x & 63;
    const int wid = (blockIdx.x * 256 + threadIdx.x) >> 6;
    const int NW = gridDim.x * 4;
    float4 xr[8][3];
#pragma unroll
    for (int b = 0; b < 8; ++b)
#pragma unroll
        for (int i = 0; i < 3; ++i)
            xr[b][i] = *reinterpret_cast<const float4*>(ws + OFF_X + b * D + 4 * lane + 256 * i);
    int j = wid;
    float4 w[3];
    if (j < V) {
#pragma unroll
        for (int i = 0; i < 3; ++i)
            w[i] = *reinterpret_cast<const float4*>(wte + (size_t)j * D + 4 * lane + 256 * i);
    }
    while (j < V) {
        int jn = j + NW;
        float4 wn[3];
        if (jn < V) {
#pragma unroll
            for (int i = 0; i < 3; ++i)
                wn[i] = *reinterpret_cast<const float4*>(wte + (size_t)jn * D + 4 * lane + 256 * i);
        }
        float acc[8] = {0};
#pragma unroll
        for (int b = 0; b < 8; ++b) {
#pragma unroll
            for (int i = 0; i < 3; ++i)
                acc[b] += w[i].x * xr[b][i].x + w[i].y * xr[b][i].y +
                          w[i].z * xr[b][i].z + w[i].w * xr[b][i].w;
        }
#pragma unroll
        for (int b = 0; b < 8; ++b) acc[b] = wsum(acc[b]);
        float v = acc[0];
#pragma unroll
        for (int bb = 1; bb < 8; ++bb) if (lane == bb) v = acc[bb];
        if (lane < 8) out[(size_t)lane * V + j] = v;
#pragma unroll
        for (int i = 0; i < 3; ++i) w[i] = wn[i];
        j = jn;
    }
}

extern "C" void kernel_launch(void* const* d_in, const int* in_sizes, int n_in,
                              void* d_out, int out_size, void* d_ws, size_t ws_size,
                              hipStream_t stream) {
    const int*   idx = (const int*)  d_in[0];
    const float* wte = (const float*)d_in[1];
    const float* wpe = (const float*)d_in[2];
    const float* wq  = (const float*)d_in[3];
    const float* wk  = (const float*)d_in[4];
    const float* wv  = (const float*)d_in[5];
    const float* wlr = (const float*)d_in[6];
    const float* w_o = (const float*)d_in[7];
    const float* w1  = (const float*)d_in[8];
    const float* w2  = (const float*)d_in[9];
    float* out = (float*)d_out;
    float* ws  = (float*)d_ws;

    // zero the atomic-accumulated regions (e_mean + A)
    hipMemsetAsync(ws, 0, (size_t)(768 + B * NS * D) * sizeof(float), stream);

    k1_emean  <<<dim3(3, 128), 256, 0, stream>>>(wte, ws);
    k2a_gq    <<<36,           256, 0, stream>>>(wpe, wq, wk, ws);
    k2b_scores<<<256,          256, 0, stream>>>(wpe, ws);
    k3_softmax<<<12,           256, 0, stream>>>(ws);
    k4_accA   <<<dim3(3, 8, 16), 256, 0, stream>>>(idx, wte, ws);
    k5_yv     <<<288,          256, 0, stream>>>(wv, wlr, ws);
    k5b_sb    <<<3,            256, 0, stream>>>(idx, wte, ws);
    k6_wo     <<<384,          256, 0, stream>>>(w_o, ws);
    k7_mlp1   <<<768,          256, 0, stream>>>(w1, ws);
    k8_mlp2   <<<192,          256, 0, stream>>>(w2, ws);
    k9_logits <<<768,          256, 0, stream>>>(wte, ws, out);
}

// Round 2
// 427.644 us; speedup vs baseline: 1.1652x; 1.1652x over previous
//
#include <hip/hip_runtime.h>
#include <math.h>

#define B 8
#define S 1024
#define D 768
#define H 12
#define V 50257
#define DFF 3072
#define HD (H*D)      // 9216
#define SLO 1012      // first s needed (head 11, last 12 positions of y feed x row 1023)
#define NS 12

// workspace layout (float offsets)
#define OFF_EMEAN 0                     // 768   (atomic sum; divide by V on read)
#define OFF_A     768                   // B*NS*D = 73728 (atomic)
#define OFF_GQ    (OFF_A + B*NS*D)      // NS*D = 9216
#define OFF_SC    (OFF_GQ + NS*D)       // NS*S = 12288 (scores -> attn in place)
#define OFF_YV    (OFF_SC + NS*S)       // B*HD = 73728
#define OFF_YO    (OFF_YV + B*HD)       // B*D = 6144
#define OFF_G     (OFF_YO + B*D)        // B*DFF = 24576
#define OFF_X     (OFF_G + B*DFF)       // B*D = 6144

__device__ __forceinline__ float wsum(float v) {
    v += __shfl_xor(v, 1, 64);
    v += __shfl_xor(v, 2, 64);
    v += __shfl_xor(v, 4, 64);
    v += __shfl_xor(v, 8, 64);
    v += __shfl_xor(v, 16, 64);
    v += __shfl_xor(v, 32, 64);
    return v;
}

// ---- K1: column sums of wte (for e_mean). float4 streaming, grid 512 x 192.
// Each block-iteration reads one full 3KB row (192 threads x 16B, coalesced).
// 4 independent accumulators keep ~64B/thread in flight -> ~6MB chip-wide.
__global__ __launch_bounds__(192) void k1_emean(const float* __restrict__ wte,
                                                float* __restrict__ ws) {
    const float4* __restrict__ wte4 = reinterpret_cast<const float4*>(wte);
    const int c = threadIdx.x;                                // 0..191 (float4 col)
    float4 a0 = {0,0,0,0}, a1 = {0,0,0,0}, a2 = {0,0,0,0}, a3 = {0,0,0,0};
    int v = blockIdx.x;
#define K1_LD(A, vv) { float4 t = wte4[(size_t)(vv) * 192 + c]; \
                       A.x += t.x; A.y += t.y; A.z += t.z; A.w += t.w; }
    for (; v + 1536 < V; v += 2048) {
        K1_LD(a0, v)
        K1_LD(a1, v + 512)
        K1_LD(a2, v + 1024)
        K1_LD(a3, v + 1536)
    }
    for (; v < V; v += 512) K1_LD(a0, v)
#undef K1_LD
    a0.x += a1.x + a2.x + a3.x;
    a0.y += a1.y + a2.y + a3.y;
    a0.z += a1.z + a2.z + a3.z;
    a0.w += a1.w + a2.w + a3.w;
    atomicAdd(&ws[OFF_EMEAN + 4 * c + 0], a0.x);
    atomicAdd(&ws[OFF_EMEAN + 4 * c + 1], a0.y);
    atomicAdd(&ws[OFF_EMEAN + 4 * c + 2], a0.z);
    atomicAdd(&ws[OFF_EMEAN + 4 * c + 3], a0.w);
}

// ---- K2a: gq[s12,d] = wpe[s+1,d]*wq[11,d]*wk[11,d]. grid 36 x 256
__global__ __launch_bounds__(256) void k2a_gq(const float* __restrict__ wpe,
                                              const float* __restrict__ wq,
                                              const float* __restrict__ wk,
                                              float* __restrict__ ws) {
    int i = blockIdx.x * 256 + threadIdx.x;                   // < 9216
    int s12 = i / D, d = i % D;
    ws[OFF_GQ + i] = wpe[(SLO + s12 + 1) * D + d] * wq[11 * D + d] * wk[11 * D + d];
}

// ---- K2b: scores[s12,t] = p[t,:] . gq[s12,:].  wave per t. grid 256 x 256
__global__ __launch_bounds__(256) void k2b_scores(const float* __restrict__ wpe,
                                                  float* __restrict__ ws) {
    const int lane = threadIdx.x & 63;
    const int t = (blockIdx.x * 256 + threadIdx.x) >> 6;      // 0..1023
    float4 p[3];
#pragma unroll
    for (int i = 0; i < 3; ++i)
        p[i] = *reinterpret_cast<const float4*>(wpe + t * D + 4 * lane + 256 * i);
    float acc[12];
#pragma unroll
    for (int s12 = 0; s12 < 12; ++s12) {
        float a = 0.f;
#pragma unroll
        for (int i = 0; i < 3; ++i) {
            float4 g = *reinterpret_cast<const float4*>(ws + OFF_GQ + s12 * D + 4 * lane + 256 * i);
            a += p[i].x * g.x + p[i].y * g.y + p[i].z * g.z + p[i].w * g.w;
        }
        acc[s12] = a;
    }
#pragma unroll
    for (int s12 = 0; s12 < 12; ++s12) acc[s12] = wsum(acc[s12]);
    float v = acc[0];
#pragma unroll
    for (int j = 1; j < 12; ++j) if (lane == j) v = acc[j];
    if (lane < 12) ws[OFF_SC + lane * S + t] = v;
}

// ---- K3: softmax rows (masked t<=s), writes attn in place (0 beyond). grid 12 x 256
__global__ __launch_bounds__(256) void k3_softmax(float* __restrict__ ws) {
    __shared__ float red[256];
    const int s12 = blockIdx.x, tid = threadIdx.x;
    const int n = SLO + s12 + 1;                              // valid t count
    float* sc = ws + OFF_SC + s12 * S;
    float m = -1e30f;
#pragma unroll
    for (int k = 0; k < 4; ++k) { int t = tid + 256 * k; if (t < n) m = fmaxf(m, sc[t]); }
    red[tid] = m; __syncthreads();
    for (int off = 128; off; off >>= 1) { if (tid < off) red[tid] = fmaxf(red[tid], red[tid + off]); __syncthreads(); }
    float mx = red[0]; __syncthreads();
    float sum = 0.f;
#pragma unroll
    for (int k = 0; k < 4; ++k) { int t = tid + 256 * k; if (t < n) sum += expf(sc[t] - mx); }
    red[tid] = sum; __syncthreads();
    for (int off = 128; off; off >>= 1) { if (tid < off) red[tid] += red[tid + off]; __syncthreads(); }
    float inv = 1.0f / red[0];
#pragma unroll
    for (int k = 0; k < 4; ++k) {
        int t = tid + 256 * k;
        sc[t] = (t < n) ? expf(sc[t] - mx) * inv : 0.0f;
    }
}

// ---- K4: A[b,s12,d] += sum_t attn[s12,t]*wte[idx[b,t],d].
// float4 gather: 192 threads cover one full row. grid (32 tc, 8 b) x 192.
__global__ __launch_bounds__(192) void k4_accA(const int* __restrict__ idx,
                                               const float* __restrict__ wte,
                                               float* __restrict__ ws) {
    const float4* __restrict__ wte4 = reinterpret_cast<const float4*>(wte);
    __shared__ float wl[32 * 12];
    const int tc = blockIdx.x, b = blockIdx.y, tid = threadIdx.x;
    for (int i = tid; i < 384; i += 192) {
        int tl = i / 12, s12 = i % 12;
        wl[i] = ws[OFF_SC + s12 * S + tc * 32 + tl];
    }
    __syncthreads();
    float4 acc[12] = {};
    const int* __restrict__ ib = idx + b * S + tc * 32;
#pragma unroll 4
    for (int tl = 0; tl < 32; ++tl) {
        int row = ib[tl];
        float4 val = wte4[(size_t)row * 192 + tid];
        const float* w = &wl[tl * 12];
#pragma unroll
        for (int s12 = 0; s12 < 12; ++s12) {
            float wv_ = w[s12];
            acc[s12].x += wv_ * val.x;
            acc[s12].y += wv_ * val.y;
            acc[s12].z += wv_ * val.z;
            acc[s12].w += wv_ * val.w;
        }
    }
#pragma unroll
    for (int s12 = 0; s12 < 12; ++s12) {
        float* dst = &ws[OFF_A + (b * NS + s12) * D + 4 * tid];
        atomicAdd(dst + 0, acc[s12].x);
        atomicAdd(dst + 1, acc[s12].y);
        atomicAdd(dst + 2, acc[s12].z);
        atomicAdd(dst + 3, acc[s12].w);
    }
}

// ---- K5: yv[b, s12*768+d] = (A - e_mean)*wv[11,d]*invn[s]*w_lr[11]. grid 288 x 256
__global__ __launch_bounds__(256) void k5_yv(const float* __restrict__ wv,
                                             const float* __restrict__ wlr,
                                             float* __restrict__ ws) {
    int i = blockIdx.x * 256 + threadIdx.x;                   // < 73728
    int b = i / HD, f = i % HD, s12 = f / D, d = f % D;
    float em = ws[OFF_EMEAN + d] * (1.0f / V);
    float A  = ws[OFF_A + (b * NS + s12) * D + d];
    float invn = 1.0f / (float)(SLO + s12 + 1);
    ws[OFF_YV + i] = (A - em) * wv[11 * D + d] * invn * wlr[11];
}

// ---- K5b: yo[b,d] initialized to sb[d] (batch-summed b_term at s=1023). grid 3 x 256
__global__ __launch_bounds__(256) void k5b_sb(const int* __restrict__ idx,
                                              const float* __restrict__ wte,
                                              float* __restrict__ ws) {
    int d = blockIdx.x * 256 + threadIdx.x;                   // < 768
    float em = ws[OFF_EMEAN + d] * (1.0f / V);
    float s = 0.f;
#pragma unroll
    for (int b = 0; b < 8; ++b) {
        int row = idx[b * S + (S - 1)];
        s += wte[(size_t)row * D + d];
    }
    float sb = (s - 8.0f * em) * (1.0f / (float)S);
#pragma unroll
    for (int b = 0; b < 8; ++b) ws[OFF_YO + b * D + d] = sb;
}

// ---- K6: yo[b,d'] += sum_f yv[b,f]*w_o[d',f].  wave = 2 rows x 1/4 of k. grid 384 x 256
__global__ __launch_bounds__(256) void k6_wo(const float* __restrict__ w_o,
                                             float* __restrict__ ws) {
    const int lane = threadIdx.x & 63;
    const int wid = (blockIdx.x * 256 + threadIdx.x) >> 6;    // 0..1535
    const int kc = wid & 3;
    const int r0 = (wid >> 2) * 2;                            // 0..766
    const int kbase = kc * 2304;
    float acc[2][8] = {{0}};
#pragma unroll
    for (int i = 0; i < 9; ++i) {
        int k = kbase + 4 * lane + 256 * i;
        float4 a0 = *reinterpret_cast<const float4*>(w_o + (size_t)r0 * HD + k);
        float4 a1 = *reinterpret_cast<const float4*>(w_o + (size_t)(r0 + 1) * HD + k);
#pragma unroll
        for (int b = 0; b < 8; ++b) {
            float4 y = *reinterpret_cast<const float4*>(ws + OFF_YV + b * HD + k);
            acc[0][b] += a0.x * y.x + a0.y * y.y + a0.z * y.z + a0.w * y.w;
            acc[1][b] += a1.x * y.x + a1.y * y.y + a1.z * y.z + a1.w * y.w;
        }
    }
#pragma unroll
    for (int r = 0; r < 2; ++r)
#pragma unroll
        for (int b = 0; b < 8; ++b) acc[r][b] = wsum(acc[r][b]);
    float v = acc[0][0];
#pragma unroll
    for (int l = 1; l < 16; ++l) if (lane == l) v = acc[l >> 3][l & 7];
    if (lane < 16) atomicAdd(&ws[OFF_YO + (lane & 7) * D + r0 + (lane >> 3)], v);
}

// ---- K7: g[b,f] = gelu(sum_d yo[b,d]*w1[f,d]).  wave per f. grid 768 x 256
__global__ __launch_bounds__(256) void k7_mlp1(const float* __restrict__ w1,
                                               float* __restrict__ ws) {
    const int lane = threadIdx.x & 63;
    const int f = (blockIdx.x * 256 + threadIdx.x) >> 6;      // 0..3071
    float acc[8] = {0};
#pragma unroll
    for (int i = 0; i < 3; ++i) {
        int dcol = 4 * lane + 256 * i;
        float4 w = *reinterpret_cast<const float4*>(w1 + (size_t)f * D + dcol);
#pragma unroll
        for (int b = 0; b < 8; ++b) {
            float4 y = *reinterpret_cast<const float4*>(ws + OFF_YO + b * D + dcol);
            acc[b] += w.x * y.x + w.y * y.y + w.z * y.z + w.w * y.w;
        }
    }
#pragma unroll
    for (int b = 0; b < 8; ++b) acc[b] = wsum(acc[b]);
    float v = acc[0];
#pragma unroll
    for (int j = 1; j < 8; ++j) if (lane == j) v = acc[j];
    if (lane < 8) {
        float g = 0.5f * v * (1.0f + erff(v * 0.70710678118654752f));
        ws[OFF_G + lane * DFF + f] = g;
    }
}

// ---- K8: x[b,d] = yo[b,d] + sum_f g[b,f]*w2[d,f].  wave per d. grid 192 x 256
__global__ __launch_bounds__(256) void k8_mlp2(const float* __restrict__ w2,
                                               float* __restrict__ ws) {
    const int lane = threadIdx.x & 63;
    const int dd = (blockIdx.x * 256 + threadIdx.x) >> 6;     // 0..767
    float acc[8] = {0};
#pragma unroll
    for (int i = 0; i < 12; ++i) {
        int fcol = 4 * lane + 256 * i;
        float4 w = *reinterpret_cast<const float4*>(w2 + (size_t)dd * DFF + fcol);
#pragma unroll
        for (int b = 0; b < 8; ++b) {
            float4 g = *reinterpret_cast<const float4*>(ws + OFF_G + b * DFF + fcol);
            acc[b] += w.x * g.x + w.y * g.y + w.z * g.z + w.w * g.w;
        }
    }
#pragma unroll
    for (int b = 0; b < 8; ++b) acc[b] = wsum(acc[b]);
    float v = acc[0];
#pragma unroll
    for (int j = 1; j < 8; ++j) if (lane == j) v = acc[j];
    if (lane < 8) ws[OFF_X + lane * D + dd] = ws[OFF_YO + lane * D + dd] + v;
}

// ---- K9: logits[b,j] = x[b,:] . wte[j,:].  wave per row, x in registers. grid 768 x 256
__global__ __launch_bounds__(256) void k9_logits(const float* __restrict__ wte,
                                                 const float* __restrict__ ws,
                                                 float* __restrict__ out) {
    const int lane = threadIdx.x & 63;
    const int wid = (blockIdx.x * 256 + threadIdx.x) >> 6;
    const int NW = gridDim.x * 4;
    float4 xr[8][3];
#pragma unroll
    for (int b = 0; b < 8; ++b)
#pragma unroll
        for (int i = 0; i < 3; ++i)
            xr[b][i] = *reinterpret_cast<const float4*>(ws + OFF_X + b * D + 4 * lane + 256 * i);
    int j = wid;
    float4 w[3];
    if (j < V) {
#pragma unroll
        for (int i = 0; i < 3; ++i)
            w[i] = *reinterpret_cast<const float4*>(wte + (size_t)j * D + 4 * lane + 256 * i);
    }
    while (j < V) {
        int jn = j + NW;
        float4 wn[3];
        if (jn < V) {
#pragma unroll
            for (int i = 0; i < 3; ++i)
                wn[i] = *reinterpret_cast<const float4*>(wte + (size_t)jn * D + 4 * lane + 256 * i);
        }
        float acc[8] = {0};
#pragma unroll
        for (int b = 0; b < 8; ++b) {
#pragma unroll
            for (int i = 0; i < 3; ++i)
                acc[b] += w[i].x * xr[b][i].x + w[i].y * xr[b][i].y +
                          w[i].z * xr[b][i].z + w[i].w * xr[b][i].w;
        }
#pragma unroll
        for (int b = 0; b < 8; ++b) acc[b] = wsum(acc[b]);
        float v = acc[0];
#pragma unroll
        for (int bb = 1; bb < 8; ++bb) if (lane == bb) v = acc[bb];
        if (lane < 8) out[(size_t)lane * V + j] = v;
#pragma unroll
        for (int i = 0; i < 3; ++i) w[i] = wn[i];
        j = jn;
    }
}

extern "C" void kernel_launch(void* const* d_in, const int* in_sizes, int n_in,
                              void* d_out, int out_size, void* d_ws, size_t ws_size,
                              hipStream_t stream) {
    const int*   idx = (const int*)  d_in[0];
    const float* wte = (const float*)d_in[1];
    const float* wpe = (const float*)d_in[2];
    const float* wq  = (const float*)d_in[3];
    const float* wk  = (const float*)d_in[4];
    const float* wv  = (const float*)d_in[5];
    const float* wlr = (const float*)d_in[6];
    const float* w_o = (const float*)d_in[7];
    const float* w1  = (const float*)d_in[8];
    const float* w2  = (const float*)d_in[9];
    float* out = (float*)d_out;
    float* ws  = (float*)d_ws;

    // zero the atomic-accumulated regions (e_mean + A)
    hipMemsetAsync(ws, 0, (size_t)(768 + B * NS * D) * sizeof(float), stream);

    k1_emean  <<<512,          192, 0, stream>>>(wte, ws);
    k2a_gq    <<<36,           256, 0, stream>>>(wpe, wq, wk, ws);
    k2b_scores<<<256,          256, 0, stream>>>(wpe, ws);
    k3_softmax<<<12,           256, 0, stream>>>(ws);
    k4_accA   <<<dim3(32, 8),  192, 0, stream>>>(idx, wte, ws);
    k5_yv     <<<288,          256, 0, stream>>>(wv, wlr, ws);
    k5b_sb    <<<3,            256, 0, stream>>>(idx, wte, ws);
    k6_wo     <<<384,          256, 0, stream>>>(w_o, ws);
    k7_mlp1   <<<768,          256, 0, stream>>>(w1, ws);
    k8_mlp2   <<<192,          256, 0, stream>>>(w2, ws);
    k9_logits <<<768,          256, 0, stream>>>(wte, ws, out);
}